// Round 18
// baseline (75.205 us; speedup 1.0000x reference)
//
#include <hip/hip_runtime.h>
#include <hip/hip_fp16.h>

// GradientCurvatureAttention: fused depthwise-conv + curvature + channel-softmax + scale.
// x: [B=16, C=128, H=128, W=128] fp32, NCHW. out: same shape.
//
// Round 18: R17 (56.5us, f16-packed state) with SHUFFLE-FREE HALOS: the 6
// ds_bpermute per iter (load->colsum->shuffle->score chain, ~30cy DS stall
// mid-iter with only ~6 resident waves) are replaced by 6 scalar halo loads
// (same L1 lines as neighbors' float4s) that issue WITH the main loads ->
// after one s_waitcnt the iter body is pure VALU. OOB-clamped at lane edges
// (values masked anyway). Everything else identical to R17.

#define GCA_B 16
#define GCA_C 128
#define GCA_H 128
#define GCA_W 128
#define CGRP  8            // channel groups (blockDim.y)
#define CPW   (GCA_C/CGRP) // 16 channels per group

#define GCA_LOG2E 1.44269504088896f

typedef float gca_f4 __attribute__((ext_vector_type(4)));  // native vec for NT store

__device__ __forceinline__ float gca_score18(float cpl, float cpc, float cpr,
                                             float cml, float cmc, float cmr,
                                             float cyl, float cyc, float cyr) {
    const float Gx  = cpl - cpr;                       // [1,2,1]v x [1,0,-1]h
    const float Gy  = fmaf(2.f, cmc, cml + cmr);       // [1,0,-1]v x [1,2,1]h
    const float Ixx = fmaf(-2.f, cpc, cpl + cpr);      // [1,2,1]v x [1,-2,1]h
    const float Ixy = cmr - cml;                       // [1,0,-1]v x [-1,0,1]h
    const float Iyy = fmaf(2.f, cyc, cyl + cyr);       // [1,-2,1]v x [1,2,1]h
    const float gy2 = Gy * Gy;
    const float g2e = fmaf(Gx, Gx, gy2 + 1e-6f);
    const float r   = __builtin_amdgcn_rsqf(g2e);      // raw v_rsq_f32
    const float gm  = g2e * r;                         // sqrt(g2e)
    const float t   = Gx * Iyy;
    const float p   = Gy * Ixy;
    const float inner = fmaf(-2.f, p, t);              // Gx*Iyy - 2*Gy*Ixy
    const float q   = gy2 * Ixx;
    const float num = fmaf(Gx, inner, q);
    const float r3  = (r * r) * r;
    return fmaf(num, r3, gm);                          // grad_mag + curvature
}

__global__ __launch_bounds__(256) void gca_fused18(const float* __restrict__ x,
                                                   float* __restrict__ out) {
    const int tx = threadIdx.x;                 // 0..31 : pixel quad, w0 = 4*tx
    const int ty = threadIdx.y;                 // 0..7  : channel group

    // XCD swizzle: 2048 blocks (= B*H, h minor), 256 consecutive ids per XCD.
    const int id  = blockIdx.x;
    const int swz = ((id & 7) << 8) | (id >> 3);
    const int h   = swz & 127;
    const int b   = swz >> 7;

    const int w0 = tx * 4;
    const int c0 = ty * CPW;

    const int hm = (h > 0) ? h - 1 : 0;
    const int hp = (h < GCA_H - 1) ? h + 1 : GCA_H - 1;
    const float mh0 = (h > 0) ? 1.f : 0.f;
    const float mh2 = (h < GCA_H - 1) ? 1.f : 0.f;
    const float mwA = (tx > 0) ? 1.f : 0.f;    // left halo exists
    const float mwB = (tx < 31) ? 1.f : 0.f;   // right halo exists
    const float mA0 = mwA * mh0, mA2 = mwA * mh2;
    const float mB0 = mwB * mh0, mB2 = mwB * mh2;
    const int dL = (tx > 0) ? -1 : 0;          // clamped halo offsets (masked anyway)
    const int dR = (tx < 31) ? 4 : 3;

    const size_t plane = (size_t)GCA_H * GCA_W;
    const float* base = x   + ((size_t)b * GCA_C + c0) * plane;
    float* obase      = out + ((size_t)b * GCA_C + c0) * plane;

    const int r0off = hm * GCA_W + w0;
    const int r1off = h  * GCA_W + w0;
    const int r2off = hp * GCA_W + w0;

    __half2 sp[CPW * 2];                 // packed scores, then packed exp values
    __half2 xp[CPW * 2];                 // packed center row for the epilogue
    float4 lmax = make_float4(-3.0e38f, -3.0e38f, -3.0e38f, -3.0e38f);

    // Pass 1: conv + curvature scores for 4 pixels x 16 channels.
    #pragma unroll
    for (int i = 0; i < CPW; ++i) {
        const float* p = base + (size_t)i * plane;
        float4 v0 = *(const float4*)(p + r0off);
        const float4 v1 = *(const float4*)(p + r1off);
        float4 v2 = *(const float4*)(p + r2off);
        float l0 = p[r0off + dL], l1 = p[r1off + dL], l2 = p[r2off + dL];
        float r0 = p[r0off + dR], r1 = p[r1off + dR], r2 = p[r2off + dR];
        xp[2 * i]     = __floats2half2_rn(v1.x, v1.y);
        xp[2 * i + 1] = __floats2half2_rn(v1.z, v1.w);

        // Masks (identity except image edges; unconditional, straight-line).
        v0.x *= mh0; v0.y *= mh0; v0.z *= mh0; v0.w *= mh0;
        v2.x *= mh2; v2.y *= mh2; v2.z *= mh2; v2.w *= mh2;
        l0 *= mA0; l1 *= mwA; l2 *= mA2;
        r0 *= mB0; r1 *= mwB; r2 *= mB2;

        // Column sums: left halo, own 4 (A..D), right halo. Pure VALU.
        const float cpL = fmaf(2.f, l1, l0 + l2);
        const float cmL = l0 - l2;
        const float cyL = fmaf(-4.f, l1, cpL);
        const float cpA = fmaf(2.f, v1.x, v0.x + v2.x);
        const float cmA = v0.x - v2.x;
        const float cyA = fmaf(-4.f, v1.x, cpA);
        const float cpB = fmaf(2.f, v1.y, v0.y + v2.y);
        const float cmB = v0.y - v2.y;
        const float cyB = fmaf(-4.f, v1.y, cpB);
        const float cpC = fmaf(2.f, v1.z, v0.z + v2.z);
        const float cmC = v0.z - v2.z;
        const float cyC = fmaf(-4.f, v1.z, cpC);
        const float cpD = fmaf(2.f, v1.w, v0.w + v2.w);
        const float cmD = v0.w - v2.w;
        const float cyD = fmaf(-4.f, v1.w, cpD);
        const float cpR = fmaf(2.f, r1, r0 + r2);
        const float cmR = r0 - r2;
        const float cyR = fmaf(-4.f, r1, cpR);

        float4 sc;
        sc.x = gca_score18(cpL, cpA, cpB,  cmL, cmA, cmB,  cyL, cyA, cyB);
        sc.y = gca_score18(cpA, cpB, cpC,  cmA, cmB, cmC,  cyA, cyB, cyC);
        sc.z = gca_score18(cpB, cpC, cpD,  cmB, cmC, cmD,  cyB, cyC, cyD);
        sc.w = gca_score18(cpC, cpD, cpR,  cmC, cmD, cmR,  cyC, cyD, cyR);
        sp[2 * i]     = __floats2half2_rn(sc.x, sc.y);
        sp[2 * i + 1] = __floats2half2_rn(sc.z, sc.w);
        lmax.x = fmaxf(lmax.x, sc.x);
        lmax.y = fmaxf(lmax.y, sc.y);
        lmax.z = fmaxf(lmax.z, sc.z);
        lmax.w = fmaxf(lmax.w, sc.w);
    }

    // Cross-group softmax reduction (per pixel, over the 8 channel groups).
    __shared__ float4 redmax[CGRP][32];
    __shared__ float4 redsum[CGRP][32];

    redmax[ty][tx] = lmax;
    __syncthreads();
    float4 gmax = make_float4(-3.0e38f, -3.0e38f, -3.0e38f, -3.0e38f);
    #pragma unroll
    for (int g = 0; g < CGRP; ++g) {
        const float4 m = redmax[g][tx];
        gmax.x = fmaxf(gmax.x, m.x);
        gmax.y = fmaxf(gmax.y, m.y);
        gmax.z = fmaxf(gmax.z, m.z);
        gmax.w = fmaxf(gmax.w, m.w);
    }

    float4 lsum = make_float4(0.f, 0.f, 0.f, 0.f);
    #pragma unroll
    for (int i = 0; i < CPW; ++i) {
        const float2 slo = __half22float2(sp[2 * i]);
        const float2 shi = __half22float2(sp[2 * i + 1]);
        float4 e;
        e.x = __builtin_amdgcn_exp2f((slo.x - gmax.x) * GCA_LOG2E);
        e.y = __builtin_amdgcn_exp2f((slo.y - gmax.y) * GCA_LOG2E);
        e.z = __builtin_amdgcn_exp2f((shi.x - gmax.z) * GCA_LOG2E);
        e.w = __builtin_amdgcn_exp2f((shi.y - gmax.w) * GCA_LOG2E);
        sp[2 * i]     = __floats2half2_rn(e.x, e.y);
        sp[2 * i + 1] = __floats2half2_rn(e.z, e.w);
        lsum.x += e.x; lsum.y += e.y; lsum.z += e.z; lsum.w += e.w;
    }
    redsum[ty][tx] = lsum;
    __syncthreads();
    float4 tot = make_float4(0.f, 0.f, 0.f, 0.f);
    #pragma unroll
    for (int g = 0; g < CGRP; ++g) {
        const float4 sm = redsum[g][tx];
        tot.x += sm.x; tot.y += sm.y; tot.z += sm.z; tot.w += sm.w;
    }
    const float invx = __builtin_amdgcn_rcpf(tot.x);
    const float invy = __builtin_amdgcn_rcpf(tot.y);
    const float invz = __builtin_amdgcn_rcpf(tot.z);
    const float invw = __builtin_amdgcn_rcpf(tot.w);

    // Epilogue: out = (softmax + 1) * x, x unpacked from registers; NT stores.
    #pragma unroll
    for (int i = 0; i < CPW; ++i) {
        const float2 elo = __half22float2(sp[2 * i]);
        const float2 ehi = __half22float2(sp[2 * i + 1]);
        const float2 xlo = __half22float2(xp[2 * i]);
        const float2 xhi = __half22float2(xp[2 * i + 1]);
        gca_f4 o;
        o.x = fmaf(elo.x * invx, xlo.x, xlo.x);
        o.y = fmaf(elo.y * invy, xlo.y, xlo.y);
        o.z = fmaf(ehi.x * invz, xhi.x, xhi.x);
        o.w = fmaf(ehi.y * invw, xhi.y, xhi.y);
        __builtin_nontemporal_store(o, (gca_f4*)(obase + (size_t)i * plane + r1off));
    }
}

extern "C" void kernel_launch(void* const* d_in, const int* in_sizes, int n_in,
                              void* d_out, int out_size, void* d_ws, size_t ws_size,
                              hipStream_t stream) {
    (void)in_sizes; (void)n_in; (void)d_ws; (void)ws_size; (void)out_size;
    const float* x = (const float*)d_in[0];
    float* out = (float*)d_out;
    dim3 block(32, CGRP, 1);
    dim3 grid(GCA_B * GCA_H, 1, 1);   // 2048 blocks, swizzled in-kernel
    gca_fused18<<<grid, block, 0, stream>>>(x, out);
}

// Round 19
// 66.117 us; speedup vs baseline: 1.1374x; 1.1374x over previous
//
#include <hip/hip_runtime.h>
#include <hip/hip_fp16.h>

// GradientCurvatureAttention: fused depthwise-conv + curvature + channel-softmax + scale.
// x: [B=16, C=128, H=128, W=128] fp32, NCHW. out: same shape.
//
// Round 19: R17 (56.5us, VGPR=84=64state+20work, occ 27%) MINUS the xp[]
// center-row cache: state halves to 32 regs (sp[] only) -> target the <=64
// VGPR class (8 waves/SIMD, like R7/R12/R14 @ occ 37%). Epilogue reloads the
// center row from L3 (R14 epilogue). Tests whether occupancy or the epilogue
// chain is binding at the current operating point. Keeps: f16-packed scores,
// NT stores, raw intrinsics, shuffle halos, CGRP=8, straight-line body.

#define GCA_B 16
#define GCA_C 128
#define GCA_H 128
#define GCA_W 128
#define CGRP  8            // channel groups (blockDim.y)
#define CPW   (GCA_C/CGRP) // 16 channels per group

#define GCA_LOG2E 1.44269504088896f

typedef float gca_f4 __attribute__((ext_vector_type(4)));  // native vec for NT store

__device__ __forceinline__ float gca_score19(float cpl, float cpc, float cpr,
                                             float cml, float cmc, float cmr,
                                             float cyl, float cyc, float cyr) {
    const float Gx  = cpl - cpr;                       // [1,2,1]v x [1,0,-1]h
    const float Gy  = fmaf(2.f, cmc, cml + cmr);       // [1,0,-1]v x [1,2,1]h
    const float Ixx = fmaf(-2.f, cpc, cpl + cpr);      // [1,2,1]v x [1,-2,1]h
    const float Ixy = cmr - cml;                       // [1,0,-1]v x [-1,0,1]h
    const float Iyy = fmaf(2.f, cyc, cyl + cyr);       // [1,-2,1]v x [1,2,1]h
    const float gy2 = Gy * Gy;
    const float g2e = fmaf(Gx, Gx, gy2 + 1e-6f);
    const float r   = __builtin_amdgcn_rsqf(g2e);      // raw v_rsq_f32
    const float gm  = g2e * r;                         // sqrt(g2e)
    const float t   = Gx * Iyy;
    const float p   = Gy * Ixy;
    const float inner = fmaf(-2.f, p, t);              // Gx*Iyy - 2*Gy*Ixy
    const float q   = gy2 * Ixx;
    const float num = fmaf(Gx, inner, q);
    const float r3  = (r * r) * r;
    return fmaf(num, r3, gm);                          // grad_mag + curvature
}

__global__ __launch_bounds__(256) void gca_fused19(const float* __restrict__ x,
                                                   float* __restrict__ out) {
    const int tx = threadIdx.x;                 // 0..31 : pixel quad, w0 = 4*tx
    const int ty = threadIdx.y;                 // 0..7  : channel group

    // XCD swizzle: 2048 blocks (= B*H, h minor), 256 consecutive ids per XCD.
    const int id  = blockIdx.x;
    const int swz = ((id & 7) << 8) | (id >> 3);
    const int h   = swz & 127;
    const int b   = swz >> 7;

    const int w0 = tx * 4;
    const int c0 = ty * CPW;

    const int hm = (h > 0) ? h - 1 : 0;
    const int hp = (h < GCA_H - 1) ? h + 1 : GCA_H - 1;
    const float mh0 = (h > 0) ? 1.f : 0.f;
    const float mh2 = (h < GCA_H - 1) ? 1.f : 0.f;
    const float mwA = (tx > 0) ? 1.f : 0.f;    // left halo exists
    const float mwB = (tx < 31) ? 1.f : 0.f;   // right halo exists

    const size_t plane = (size_t)GCA_H * GCA_W;
    const float* base = x   + ((size_t)b * GCA_C + c0) * plane;
    float* obase      = out + ((size_t)b * GCA_C + c0) * plane;

    const int r0off = hm * GCA_W + w0;
    const int r1off = h  * GCA_W + w0;
    const int r2off = hp * GCA_W + w0;

    __half2 sp[CPW * 2];                 // packed scores, then packed exp values
    float4 lmax = make_float4(-3.0e38f, -3.0e38f, -3.0e38f, -3.0e38f);

    // Pass 1: conv + curvature scores for 4 pixels x 16 channels.
    #pragma unroll
    for (int i = 0; i < CPW; ++i) {
        const float* p = base + (size_t)i * plane;
        float4 v0 = *(const float4*)(p + r0off);
        const float4 v1 = *(const float4*)(p + r1off);
        float4 v2 = *(const float4*)(p + r2off);

        // Row-edge masks (identity except h=0 / h=127; unconditional to keep
        // the unrolled body straight-line).
        v0.x *= mh0; v0.y *= mh0; v0.z *= mh0; v0.w *= mh0;
        v2.x *= mh2; v2.y *= mh2; v2.z *= mh2; v2.w *= mh2;

        // Own column sums for cols w0..w0+3 (A..D).
        const float cpA = fmaf(2.f, v1.x, v0.x + v2.x);
        const float cmA = v0.x - v2.x;
        const float cyA = fmaf(-4.f, v1.x, cpA);
        const float cpB = fmaf(2.f, v1.y, v0.y + v2.y);
        const float cmB = v0.y - v2.y;
        const float cyB = fmaf(-4.f, v1.y, cpB);
        const float cpC = fmaf(2.f, v1.z, v0.z + v2.z);
        const float cmC = v0.z - v2.z;
        const float cyC = fmaf(-4.f, v1.z, cpC);
        const float cpD = fmaf(2.f, v1.w, v0.w + v2.w);
        const float cmD = v0.w - v2.w;
        const float cyD = fmaf(-4.f, v1.w, cpD);

        // Halo column sums from neighbor lanes (row masks already applied).
        const float cpL = __shfl_up(cpD, 1) * mwA;
        const float cmL = __shfl_up(cmD, 1) * mwA;
        const float cyL = __shfl_up(cyD, 1) * mwA;
        const float cpR = __shfl_down(cpA, 1) * mwB;
        const float cmR = __shfl_down(cmA, 1) * mwB;
        const float cyR = __shfl_down(cyA, 1) * mwB;

        float4 sc;
        sc.x = gca_score19(cpL, cpA, cpB,  cmL, cmA, cmB,  cyL, cyA, cyB);
        sc.y = gca_score19(cpA, cpB, cpC,  cmA, cmB, cmC,  cyA, cyB, cyC);
        sc.z = gca_score19(cpB, cpC, cpD,  cmB, cmC, cmD,  cyB, cyC, cyD);
        sc.w = gca_score19(cpC, cpD, cpR,  cmC, cmD, cmR,  cyC, cyD, cyR);
        sp[2 * i]     = __floats2half2_rn(sc.x, sc.y);
        sp[2 * i + 1] = __floats2half2_rn(sc.z, sc.w);
        lmax.x = fmaxf(lmax.x, sc.x);
        lmax.y = fmaxf(lmax.y, sc.y);
        lmax.z = fmaxf(lmax.z, sc.z);
        lmax.w = fmaxf(lmax.w, sc.w);
    }

    // Cross-group softmax reduction (per pixel, over the 8 channel groups).
    __shared__ float4 redmax[CGRP][32];
    __shared__ float4 redsum[CGRP][32];

    redmax[ty][tx] = lmax;
    __syncthreads();
    float4 gmax = make_float4(-3.0e38f, -3.0e38f, -3.0e38f, -3.0e38f);
    #pragma unroll
    for (int g = 0; g < CGRP; ++g) {
        const float4 m = redmax[g][tx];
        gmax.x = fmaxf(gmax.x, m.x);
        gmax.y = fmaxf(gmax.y, m.y);
        gmax.z = fmaxf(gmax.z, m.z);
        gmax.w = fmaxf(gmax.w, m.w);
    }

    float4 lsum = make_float4(0.f, 0.f, 0.f, 0.f);
    #pragma unroll
    for (int i = 0; i < CPW; ++i) {
        const float2 slo = __half22float2(sp[2 * i]);
        const float2 shi = __half22float2(sp[2 * i + 1]);
        float4 e;
        e.x = __builtin_amdgcn_exp2f((slo.x - gmax.x) * GCA_LOG2E);
        e.y = __builtin_amdgcn_exp2f((slo.y - gmax.y) * GCA_LOG2E);
        e.z = __builtin_amdgcn_exp2f((shi.x - gmax.z) * GCA_LOG2E);
        e.w = __builtin_amdgcn_exp2f((shi.y - gmax.w) * GCA_LOG2E);
        sp[2 * i]     = __floats2half2_rn(e.x, e.y);
        sp[2 * i + 1] = __floats2half2_rn(e.z, e.w);
        lsum.x += e.x; lsum.y += e.y; lsum.z += e.z; lsum.w += e.w;
    }
    redsum[ty][tx] = lsum;
    __syncthreads();
    float4 tot = make_float4(0.f, 0.f, 0.f, 0.f);
    #pragma unroll
    for (int g = 0; g < CGRP; ++g) {
        const float4 sm = redsum[g][tx];
        tot.x += sm.x; tot.y += sm.y; tot.z += sm.z; tot.w += sm.w;
    }
    const float invx = __builtin_amdgcn_rcpf(tot.x);
    const float invy = __builtin_amdgcn_rcpf(tot.y);
    const float invz = __builtin_amdgcn_rcpf(tot.z);
    const float invw = __builtin_amdgcn_rcpf(tot.w);

    // Epilogue: out = (softmax + 1) * x; center row reloaded (L3-resident).
    #pragma unroll
    for (int i = 0; i < CPW; ++i) {
        const float4 xv = *(const float4*)(base + (size_t)i * plane + r1off);
        const float2 elo = __half22float2(sp[2 * i]);
        const float2 ehi = __half22float2(sp[2 * i + 1]);
        gca_f4 o;
        o.x = fmaf(elo.x * invx, xv.x, xv.x);
        o.y = fmaf(elo.y * invy, xv.y, xv.y);
        o.z = fmaf(ehi.x * invz, xv.z, xv.z);
        o.w = fmaf(ehi.y * invw, xv.w, xv.w);
        __builtin_nontemporal_store(o, (gca_f4*)(obase + (size_t)i * plane + r1off));
    }
}

extern "C" void kernel_launch(void* const* d_in, const int* in_sizes, int n_in,
                              void* d_out, int out_size, void* d_ws, size_t ws_size,
                              hipStream_t stream) {
    (void)in_sizes; (void)n_in; (void)d_ws; (void)ws_size; (void)out_size;
    const float* x = (const float*)d_in[0];
    float* out = (float*)d_out;
    dim3 block(32, CGRP, 1);
    dim3 grid(GCA_B * GCA_H, 1, 1);   // 2048 blocks, swizzled in-kernel
    gca_fused19<<<grid, block, 0, stream>>>(x, out);
}

// Round 20
// 56.740 us; speedup vs baseline: 1.3254x; 1.1653x over previous
//
#include <hip/hip_runtime.h>
#include <hip/hip_fp16.h>

// GradientCurvatureAttention: fused depthwise-conv + curvature + channel-softmax + scale.
// x: [B=16, C=128, H=128, W=128] fp32, NCHW. out: same shape.
//
// FINAL (= Round 17, session best: 56.5us, 17.8x over round-1 baseline).
// Structure: one fused kernel; block (32,8)=256 (tx = 4-pixel quad via float4,
// ty = channel group of 16); grid 2048 = B*H with h-contiguous XCD swizzle.
// Per-channel: 3 float4 row loads -> separable column sums (cp/cm/cy) ->
// halo columns via 1-lane shuffles -> 5 conv results as outer products ->
// curvature score. Channel softmax reduced across the 8 groups via LDS.
// Wins stacked: spill-free straight-line body (VGPR 84), f16-packed s[]/xc[]
// state, raw v_rsq/v_exp/v_rcp, non-temporal float4 stores, center-row cached
// in registers. Falsified levers (kept OUT): forced launch bounds / in-loop
// branches / manual prefetch (VGPR explosion), 2 rows/thread (occupancy),
// scalar halo loads (VGPR), CGRP=16 (allocation class unchanged, reduction 4x).

#define GCA_B 16
#define GCA_C 128
#define GCA_H 128
#define GCA_W 128
#define CGRP  8            // channel groups (blockDim.y)
#define CPW   (GCA_C/CGRP) // 16 channels per group

#define GCA_LOG2E 1.44269504088896f

typedef float gca_f4 __attribute__((ext_vector_type(4)));  // native vec for NT store

__device__ __forceinline__ float gca_score17(float cpl, float cpc, float cpr,
                                             float cml, float cmc, float cmr,
                                             float cyl, float cyc, float cyr) {
    const float Gx  = cpl - cpr;                       // [1,2,1]v x [1,0,-1]h
    const float Gy  = fmaf(2.f, cmc, cml + cmr);       // [1,0,-1]v x [1,2,1]h
    const float Ixx = fmaf(-2.f, cpc, cpl + cpr);      // [1,2,1]v x [1,-2,1]h
    const float Ixy = cmr - cml;                       // [1,0,-1]v x [-1,0,1]h
    const float Iyy = fmaf(2.f, cyc, cyl + cyr);       // [1,-2,1]v x [1,2,1]h
    const float gy2 = Gy * Gy;
    const float g2e = fmaf(Gx, Gx, gy2 + 1e-6f);
    const float r   = __builtin_amdgcn_rsqf(g2e);      // raw v_rsq_f32
    const float gm  = g2e * r;                         // sqrt(g2e)
    const float t   = Gx * Iyy;
    const float p   = Gy * Ixy;
    const float inner = fmaf(-2.f, p, t);              // Gx*Iyy - 2*Gy*Ixy
    const float q   = gy2 * Ixx;
    const float num = fmaf(Gx, inner, q);
    const float r3  = (r * r) * r;
    return fmaf(num, r3, gm);                          // grad_mag + curvature
}

__global__ __launch_bounds__(256) void gca_fused_final(const float* __restrict__ x,
                                                       float* __restrict__ out) {
    const int tx = threadIdx.x;                 // 0..31 : pixel quad, w0 = 4*tx
    const int ty = threadIdx.y;                 // 0..7  : channel group

    // XCD swizzle: 2048 blocks (= B*H, h minor), 256 consecutive ids per XCD.
    const int id  = blockIdx.x;
    const int swz = ((id & 7) << 8) | (id >> 3);
    const int h   = swz & 127;
    const int b   = swz >> 7;

    const int w0 = tx * 4;
    const int c0 = ty * CPW;

    const int hm = (h > 0) ? h - 1 : 0;
    const int hp = (h < GCA_H - 1) ? h + 1 : GCA_H - 1;
    const float mh0 = (h > 0) ? 1.f : 0.f;
    const float mh2 = (h < GCA_H - 1) ? 1.f : 0.f;
    const float mwA = (tx > 0) ? 1.f : 0.f;    // left halo exists
    const float mwB = (tx < 31) ? 1.f : 0.f;   // right halo exists

    const size_t plane = (size_t)GCA_H * GCA_W;
    const float* base = x   + ((size_t)b * GCA_C + c0) * plane;
    float* obase      = out + ((size_t)b * GCA_C + c0) * plane;

    const int r0off = hm * GCA_W + w0;
    const int r1off = h  * GCA_W + w0;
    const int r2off = hp * GCA_W + w0;

    __half2 sp[CPW * 2];                 // packed scores, then packed exp values
    __half2 xp[CPW * 2];                 // packed center row for the epilogue
    float4 lmax = make_float4(-3.0e38f, -3.0e38f, -3.0e38f, -3.0e38f);

    // Pass 1: conv + curvature scores for 4 pixels x 16 channels.
    #pragma unroll
    for (int i = 0; i < CPW; ++i) {
        const float* p = base + (size_t)i * plane;
        float4 v0 = *(const float4*)(p + r0off);
        const float4 v1 = *(const float4*)(p + r1off);
        float4 v2 = *(const float4*)(p + r2off);
        xp[2 * i]     = __floats2half2_rn(v1.x, v1.y);
        xp[2 * i + 1] = __floats2half2_rn(v1.z, v1.w);

        // Row-edge masks (identity except h=0 / h=127; unconditional to keep
        // the unrolled body straight-line).
        v0.x *= mh0; v0.y *= mh0; v0.z *= mh0; v0.w *= mh0;
        v2.x *= mh2; v2.y *= mh2; v2.z *= mh2; v2.w *= mh2;

        // Own column sums for cols w0..w0+3 (A..D).
        const float cpA = fmaf(2.f, v1.x, v0.x + v2.x);
        const float cmA = v0.x - v2.x;
        const float cyA = fmaf(-4.f, v1.x, cpA);
        const float cpB = fmaf(2.f, v1.y, v0.y + v2.y);
        const float cmB = v0.y - v2.y;
        const float cyB = fmaf(-4.f, v1.y, cpB);
        const float cpC = fmaf(2.f, v1.z, v0.z + v2.z);
        const float cmC = v0.z - v2.z;
        const float cyC = fmaf(-4.f, v1.z, cpC);
        const float cpD = fmaf(2.f, v1.w, v0.w + v2.w);
        const float cmD = v0.w - v2.w;
        const float cyD = fmaf(-4.f, v1.w, cpD);

        // Halo column sums from neighbor lanes (row masks already applied).
        const float cpL = __shfl_up(cpD, 1) * mwA;
        const float cmL = __shfl_up(cmD, 1) * mwA;
        const float cyL = __shfl_up(cyD, 1) * mwA;
        const float cpR = __shfl_down(cpA, 1) * mwB;
        const float cmR = __shfl_down(cmA, 1) * mwB;
        const float cyR = __shfl_down(cyA, 1) * mwB;

        float4 sc;
        sc.x = gca_score17(cpL, cpA, cpB,  cmL, cmA, cmB,  cyL, cyA, cyB);
        sc.y = gca_score17(cpA, cpB, cpC,  cmA, cmB, cmC,  cyA, cyB, cyC);
        sc.z = gca_score17(cpB, cpC, cpD,  cmB, cmC, cmD,  cyB, cyC, cyD);
        sc.w = gca_score17(cpC, cpD, cpR,  cmC, cmD, cmR,  cyC, cyD, cyR);
        sp[2 * i]     = __floats2half2_rn(sc.x, sc.y);
        sp[2 * i + 1] = __floats2half2_rn(sc.z, sc.w);
        lmax.x = fmaxf(lmax.x, sc.x);
        lmax.y = fmaxf(lmax.y, sc.y);
        lmax.z = fmaxf(lmax.z, sc.z);
        lmax.w = fmaxf(lmax.w, sc.w);
    }

    // Cross-group softmax reduction (per pixel, over the 8 channel groups).
    __shared__ float4 redmax[CGRP][32];
    __shared__ float4 redsum[CGRP][32];

    redmax[ty][tx] = lmax;
    __syncthreads();
    float4 gmax = make_float4(-3.0e38f, -3.0e38f, -3.0e38f, -3.0e38f);
    #pragma unroll
    for (int g = 0; g < CGRP; ++g) {
        const float4 m = redmax[g][tx];
        gmax.x = fmaxf(gmax.x, m.x);
        gmax.y = fmaxf(gmax.y, m.y);
        gmax.z = fmaxf(gmax.z, m.z);
        gmax.w = fmaxf(gmax.w, m.w);
    }

    float4 lsum = make_float4(0.f, 0.f, 0.f, 0.f);
    #pragma unroll
    for (int i = 0; i < CPW; ++i) {
        const float2 slo = __half22float2(sp[2 * i]);
        const float2 shi = __half22float2(sp[2 * i + 1]);
        float4 e;
        e.x = __builtin_amdgcn_exp2f((slo.x - gmax.x) * GCA_LOG2E);
        e.y = __builtin_amdgcn_exp2f((slo.y - gmax.y) * GCA_LOG2E);
        e.z = __builtin_amdgcn_exp2f((shi.x - gmax.z) * GCA_LOG2E);
        e.w = __builtin_amdgcn_exp2f((shi.y - gmax.w) * GCA_LOG2E);
        sp[2 * i]     = __floats2half2_rn(e.x, e.y);
        sp[2 * i + 1] = __floats2half2_rn(e.z, e.w);
        lsum.x += e.x; lsum.y += e.y; lsum.z += e.z; lsum.w += e.w;
    }
    redsum[ty][tx] = lsum;
    __syncthreads();
    float4 tot = make_float4(0.f, 0.f, 0.f, 0.f);
    #pragma unroll
    for (int g = 0; g < CGRP; ++g) {
        const float4 sm = redsum[g][tx];
        tot.x += sm.x; tot.y += sm.y; tot.z += sm.z; tot.w += sm.w;
    }
    const float invx = __builtin_amdgcn_rcpf(tot.x);
    const float invy = __builtin_amdgcn_rcpf(tot.y);
    const float invz = __builtin_amdgcn_rcpf(tot.z);
    const float invw = __builtin_amdgcn_rcpf(tot.w);

    // Epilogue: out = (softmax + 1) * x, x unpacked from registers; NT stores.
    #pragma unroll
    for (int i = 0; i < CPW; ++i) {
        const float2 elo = __half22float2(sp[2 * i]);
        const float2 ehi = __half22float2(sp[2 * i + 1]);
        const float2 xlo = __half22float2(xp[2 * i]);
        const float2 xhi = __half22float2(xp[2 * i + 1]);
        gca_f4 o;
        o.x = fmaf(elo.x * invx, xlo.x, xlo.x);
        o.y = fmaf(elo.y * invy, xlo.y, xlo.y);
        o.z = fmaf(ehi.x * invz, xhi.x, xhi.x);
        o.w = fmaf(ehi.y * invw, xhi.y, xhi.y);
        __builtin_nontemporal_store(o, (gca_f4*)(obase + (size_t)i * plane + r1off));
    }
}

extern "C" void kernel_launch(void* const* d_in, const int* in_sizes, int n_in,
                              void* d_out, int out_size, void* d_ws, size_t ws_size,
                              hipStream_t stream) {
    (void)in_sizes; (void)n_in; (void)d_ws; (void)ws_size; (void)out_size;
    const float* x = (const float*)d_in[0];
    float* out = (float*)d_out;
    dim3 block(32, CGRP, 1);
    dim3 grid(GCA_B * GCA_H, 1, 1);   // 2048 blocks, swizzled in-kernel
    gca_fused_final<<<grid, block, 0, stream>>>(x, out);
}